// Round 2
// baseline (173.337 us; speedup 1.0000x reference)
//
#include <hip/hip_runtime.h>
#include <hip/hip_bf16.h>
#include <stdint.h>

#define KD 512
#define OD 8
#define SZ (KD*KD*OD)       // 2097152 elements per tensor (A,B,C)
#define PLANE (KD*KD)       // 262144

typedef short v8s __attribute__((ext_vector_type(8)));
typedef float v4f __attribute__((ext_vector_type(4)));

#define GLOBAL_AS __attribute__((address_space(1)))
#define LDS_AS __attribute__((address_space(3)))

static __device__ __forceinline__ unsigned short f2bf(float f) {
    union { float f; unsigned int u; } v; v.f = f;
    unsigned int u = v.u;
    unsigned int r = u + 0x7FFF + ((u >> 16) & 1);   // RNE
    return (unsigned short)(r >> 16);
}

static __device__ __forceinline__ void async16(const unsigned short* g, unsigned short* l) {
    __builtin_amdgcn_global_load_lds((const GLOBAL_AS void*)g, (LDS_AS void*)l, 16, 0, 0);
}

// ---------------------------------------------------------------------------
// Pack: W[x][j][k] = A[j,k,x]*Pb[j]*Pc[k]   (bf16, k-contiguous)
//       X[y][i][k] = B[k,i,y]*Pa[i]         (bf16, k-contiguous, via LDS transpose)
// blocks [0,512): A-pack (one j per block). blocks [512,768): B-pack 32x32 tiles.
// block 0 also zeroes the probs accumulator (ws is poisoned 0xAA each call).
// ---------------------------------------------------------------------------
__global__ __launch_bounds__(256) void pack_kernel(const float* __restrict__ yp,
                                                   unsigned short* __restrict__ Wbf,
                                                   unsigned short* __restrict__ Xbf,
                                                   float* __restrict__ probs_acc) {
    __shared__ unsigned short lds[8 * 32 * 40];   // [y][di][dk], dk padded 32->40
    const float* Pa = yp;
    const float* Pb = yp + KD;
    const float* Pc = yp + 2 * KD;
    const float* A  = yp + 3 * KD;
    const float* B  = A + SZ;
    const int b = blockIdx.x;
    const int t = threadIdx.x;

    if (b == 0) { probs_acc[t] = 0.0f; probs_acc[t + 256] = 0.0f; }

    if (b < 512) {
        // ---- A-pack: j = b, each thread handles k0 = 2t, 2t+1 ----
        const int j = b;
        const float pb = Pb[j];
        const int k0 = 2 * t;
        const float4* src = (const float4*)(A + ((size_t)j * KD + k0) * 8);
        float av[16];
        ((float4*)av)[0] = src[0];
        ((float4*)av)[1] = src[1];
        ((float4*)av)[2] = src[2];
        ((float4*)av)[3] = src[3];
        const float s0 = pb * Pc[k0];
        const float s1 = pb * Pc[k0 + 1];
        #pragma unroll
        for (int x = 0; x < 8; ++x) {
            ushort2 w;
            w.x = f2bf(av[x] * s0);
            w.y = f2bf(av[8 + x] * s1);
            *(ushort2*)(Wbf + (size_t)x * PLANE + (size_t)j * KD + k0) = w;
        }
    } else {
        // ---- B-pack: transpose [k][i] -> [i][k] through LDS ----
        const int tb = b - 512;
        const int k0 = (tb / 16) * 32;
        const int i0 = (tb % 16) * 32;
        #pragma unroll
        for (int p = 0; p < 4; ++p) {
            const int idx = t + p * 256;
            const int dk = idx >> 5;
            const int di = idx & 31;
            const float pa = Pa[i0 + di];
            const float4* src = (const float4*)(B + ((size_t)(k0 + dk) * KD + (i0 + di)) * 8);
            float bv[8];
            ((float4*)bv)[0] = src[0];
            ((float4*)bv)[1] = src[1];
            #pragma unroll
            for (int y = 0; y < 8; ++y)
                lds[(y * 32 + di) * 40 + dk] = f2bf(bv[y] * pa);
        }
        __syncthreads();
        #pragma unroll
        for (int p = 0; p < 4; ++p) {
            const int c = t + p * 256;
            const int y = c >> 7;
            const int rem = c & 127;
            const int di = rem >> 2;
            const int dk8 = (rem & 3) * 8;
            uint4 v = *(const uint4*)&lds[(y * 32 + di) * 40 + dk8];
            *(uint4*)(Xbf + (size_t)y * PLANE + (size_t)(i0 + di) * KD + (k0 + dk8)) = v;
        }
    }
}

// ---------------------------------------------------------------------------
// Fused GEMM + C-contraction, x-grouped.
// grid = 1024: bid -> y (8) x i-tile (4, 128 rows) x j-tile (32, 16 cols).
// Block computes T_xy[i-tile, j-tile] for ALL 8 x (W planes) sharing X frags,
// then contracts with the 64 KB C slab (read once, reused for all 8 x).
// LDS staging is XOR-swizzled so frag ds_read_b128 are 2-way (free).
// ---------------------------------------------------------------------------
__global__ __launch_bounds__(256) void gemm_kernel(const float* __restrict__ yp,
                                                   const unsigned short* __restrict__ Wbf,
                                                   const unsigned short* __restrict__ Xbf,
                                                   float* __restrict__ probs_acc) {
    __shared__ union {
        unsigned short stage[2][128 * 32];   // [0]=Xs 128 i-rows, [1]=Ws 128 (x,j)-rows
        float red[4 * 64 * 16];              // per-wave 4KB transpose-reduce region
    } sh;

    const int bid = blockIdx.x;
    const int y  = bid & 7;
    const int it = (bid >> 3) & 3;
    const int jt = bid >> 5;              // 0..31
    const int i0 = it * 128;
    const int j0 = jt * 16;

    const unsigned short* Xg = Xbf + (size_t)y * PLANE;   // [i][k]

    const int t = threadIdx.x;
    const int w = t >> 6;                 // wave 0..3
    const int l = t & 63;
    const int lm = l & 15, quad = l >> 4;

    // staging lane geometry: lane l -> LDS slot (row=l>>2, chunk=l&3);
    // fetches global k-chunk g so that slot (r,c) holds chunk c ^ ((r>>1)&3).
    const int srow = l >> 2;
    const int gchunk = (l & 3) ^ ((l >> 3) & 3);

    v4f acc[2][8];
    #pragma unroll
    for (int mt = 0; mt < 2; ++mt)
        #pragma unroll
        for (int x = 0; x < 8; ++x)
            acc[mt][x] = (v4f){0.f, 0.f, 0.f, 0.f};

    // per-wave staging sources: waves 0,1 stage Xs (64 rows each);
    // waves 2,3 stage Ws (x = (w-2)*4 + a, 16 j-rows each).
    const unsigned short* gsrc[4];
    unsigned short* ldst[4];
    if (w < 2) {
        #pragma unroll
        for (int a = 0; a < 4; ++a) {
            const int row = w * 64 + a * 16;
            gsrc[a] = Xg + (size_t)(i0 + row + srow) * KD + gchunk * 8;
            ldst[a] = &sh.stage[0][row * 32];
        }
    } else {
        #pragma unroll
        for (int a = 0; a < 4; ++a) {
            const int x = (w - 2) * 4 + a;
            const int row = (w - 2) * 64 + a * 16;
            gsrc[a] = Wbf + (size_t)x * PLANE + (size_t)(j0 + srow) * KD + gchunk * 8;
            ldst[a] = &sh.stage[1][row * 32];
        }
    }

    const int c = quad ^ ((lm >> 1) & 3);   // swizzled read chunk

    for (int kt = 0; kt < 16; ++kt) {
        const int kb = kt * 32;
        #pragma unroll
        for (int a = 0; a < 4; ++a)
            async16(gsrc[a] + kb, ldst[a]);
        __syncthreads();

        v8s aF[2], bF[8];
        #pragma unroll
        for (int mt = 0; mt < 2; ++mt)
            aF[mt] = *(const v8s*)&sh.stage[0][(w * 32 + mt * 16 + lm) * 32 + c * 8];
        #pragma unroll
        for (int x = 0; x < 8; ++x)
            bF[x] = *(const v8s*)&sh.stage[1][(x * 16 + lm) * 32 + c * 8];
        #pragma unroll
        for (int mt = 0; mt < 2; ++mt)
            #pragma unroll
            for (int x = 0; x < 8; ++x)
                acc[mt][x] = __builtin_amdgcn_mfma_f32_16x16x32_bf16(
                    aF[mt], bF[x], acc[mt][x], 0, 0, 0);
        __syncthreads();
    }

    // ---- epilogue: probs[x,y,z] += sum_{i,j} T[x][i,j] * C[i,j,z] ----
    // D layout: row(i) = quad*4+r, col(j) = lm. C slab read once per zh pass.
    const float* Cptr = yp + 3 * KD + 2 * (size_t)SZ;
    const int ibase = i0 + w * 32;
    float* wr = &sh.red[(w * 64 + l) * 16];

    #pragma unroll
    for (int zh = 0; zh < 2; ++zh) {
        float zacc[8][4];
        #pragma unroll
        for (int x = 0; x < 8; ++x)
            #pragma unroll
            for (int zq = 0; zq < 4; ++zq) zacc[x][zq] = 0.f;

        #pragma unroll
        for (int mt = 0; mt < 2; ++mt) {
            #pragma unroll
            for (int r = 0; r < 4; ++r) {
                const int gi = ibase + mt * 16 + quad * 4 + r;
                const int gj = j0 + lm;
                const float4 cv = *(const float4*)(Cptr + ((size_t)gi * KD + gj) * 8 + zh * 4);
                #pragma unroll
                for (int x = 0; x < 8; ++x) {
                    const float tv = acc[mt][x][r];
                    zacc[x][0] += tv * cv.x;
                    zacc[x][1] += tv * cv.y;
                    zacc[x][2] += tv * cv.z;
                    zacc[x][3] += tv * cv.w;
                }
            }
        }

        // reduce 32 vals/lane over the wave in 2 sub-passes of 16 (per-wave
        // 4KB LDS region overlaid on dead staging; wave-synchronous, no barrier)
        #pragma unroll
        for (int xh = 0; xh < 2; ++xh) {
            #pragma unroll
            for (int xi = 0; xi < 4; ++xi) {
                const int x = xh * 4 + xi;
                ((float4*)wr)[xi] = make_float4(zacc[x][0], zacc[x][1],
                                                zacc[x][2], zacc[x][3]);
            }
            float s = 0.f;
            const int base = (w * 64 + quad * 16) * 16 + lm;
            #pragma unroll
            for (int rr = 0; rr < 16; ++rr)
                s += sh.red[base + rr * 16];
            s += __shfl_xor(s, 16, 64);
            s += __shfl_xor(s, 32, 64);
            if (l < 16) {
                const int x = xh * 4 + (l >> 2);
                const int zq = l & 3;
                atomicAdd(&probs_acc[(x * 8 + y) * 8 + zh * 4 + zq], s);
            }
        }
    }
}

// ---------------------------------------------------------------------------
// Finalize: KL divergence + emit probs. out[0]=d, out[1..512]=probs.
// ---------------------------------------------------------------------------
__global__ __launch_bounds__(512) void finalize_kernel(const float* __restrict__ probs_acc,
                                                       const float* __restrict__ y_true,
                                                       float* __restrict__ out) {
    __shared__ float red[8];
    const int t = threadIdx.x;
    const float p = probs_acc[t];
    out[1 + t] = p;
    const float ytv = y_true[t];
    const float pc = fminf(fmaxf(p, 1e-10f), 1.0f);
    float term = ytv * (logf(ytv + 1e-10f) - logf(pc));
    for (int off = 32; off > 0; off >>= 1)
        term += __shfl_xor(term, off, 64);
    if ((t & 63) == 0) red[t >> 6] = term;
    __syncthreads();
    if (t == 0) {
        float s = 0.f;
        #pragma unroll
        for (int i = 0; i < 8; ++i) s += red[i];
        out[0] = s;
    }
}

extern "C" void kernel_launch(void* const* d_in, const int* in_sizes, int n_in,
                              void* d_out, int out_size, void* d_ws, size_t ws_size,
                              hipStream_t stream) {
    const float* yp = (const float*)d_in[0];
    const float* yt = (const float*)d_in[1];
    float* out = (float*)d_out;

    unsigned short* Wbf = (unsigned short*)d_ws;              // 8 planes of A-weighted: 4 MB
    unsigned short* Xbf = Wbf + (size_t)8 * PLANE;            // 8 planes of B-weighted: 4 MB
    float* probs_acc = (float*)(Xbf + (size_t)8 * PLANE);     // 512 floats

    pack_kernel<<<768, 256, 0, stream>>>(yp, Wbf, Xbf, probs_acc);
    gemm_kernel<<<1024, 256, 0, stream>>>(yp, Wbf, Xbf, probs_acc);
    finalize_kernel<<<1, 512, 0, stream>>>(probs_acc, yt, out);
}

// Round 4
// 173.245 us; speedup vs baseline: 1.0005x; 1.0005x over previous
//
#include <hip/hip_runtime.h>
#include <hip/hip_bf16.h>
#include <stdint.h>

#define KD 512
#define OD 8
#define SZ (KD*KD*OD)       // 2097152 elements per tensor (A,B,C)
#define PLANE (KD*KD)       // 262144

typedef short v8s __attribute__((ext_vector_type(8)));
typedef float v4f __attribute__((ext_vector_type(4)));

#define GLOBAL_AS __attribute__((address_space(1)))
#define LDS_AS __attribute__((address_space(3)))

static __device__ __forceinline__ unsigned short f2bf(float f) {
    union { float f; unsigned int u; } v; v.f = f;
    unsigned int u = v.u;
    unsigned int r = u + 0x7FFF + ((u >> 16) & 1);   // RNE
    return (unsigned short)(r >> 16);
}

static __device__ __forceinline__ void async16(const unsigned short* g, unsigned short* l) {
    __builtin_amdgcn_global_load_lds((const GLOBAL_AS void*)g, (LDS_AS void*)l, 16, 0, 0);
}

// ---------------------------------------------------------------------------
// Pack (512 blocks): W[x][j][k]=A[j,k,x]*Pb[j]*Pc[k], X[y][i][k]=B[k,i,y]*Pa[i]
// (bf16, k-contiguous). Each block: A-pack row j=b + B-pack 16k x 32i x 8y
// transpose tile. Block 0 zeroes probs accumulator + completion counter
// (ws is re-poisoned 0xAA before every call).
// ---------------------------------------------------------------------------
__global__ __launch_bounds__(256) void pack_kernel(const float* __restrict__ yp,
                                                   unsigned short* __restrict__ Wbf,
                                                   unsigned short* __restrict__ Xbf,
                                                   float* __restrict__ probs_acc,
                                                   unsigned int* __restrict__ counter) {
    __shared__ unsigned short lds[8 * 32 * 24];   // [y][di][dk], dk padded 16->24
    const float* Pa = yp;
    const float* Pb = yp + KD;
    const float* Pc = yp + 2 * KD;
    const float* A  = yp + 3 * KD;
    const float* B  = A + SZ;
    const int b = blockIdx.x;
    const int t = threadIdx.x;

    if (b == 0) {
        probs_acc[t] = 0.f;
        probs_acc[t + 256] = 0.f;
        if (t == 0) *counter = 0u;
    }

    {   // ---- A-pack: j = b, thread t covers k = 2t, 2t+1 ----
        const int j = b;
        const float pb = Pb[j];
        const int k0 = 2 * t;
        const float4* src = (const float4*)(A + ((size_t)j * KD + k0) * 8);
        float av[16];
        ((float4*)av)[0] = src[0];
        ((float4*)av)[1] = src[1];
        ((float4*)av)[2] = src[2];
        ((float4*)av)[3] = src[3];
        const float s0 = pb * Pc[k0];
        const float s1 = pb * Pc[k0 + 1];
        #pragma unroll
        for (int x = 0; x < 8; ++x) {
            ushort2 wv;
            wv.x = f2bf(av[x] * s0);
            wv.y = f2bf(av[8 + x] * s1);
            *(ushort2*)(Wbf + (size_t)x * PLANE + (size_t)j * KD + k0) = wv;
        }
    }
    {   // ---- B-pack: 16k x 32i x 8y sub-tile, transpose [k][i]->[i][k] ----
        const int k0 = (b >> 4) * 16;
        const int i0 = (b & 15) * 32;
        #pragma unroll
        for (int p = 0; p < 2; ++p) {
            const int idx = t + p * 256;
            const int dk = idx >> 5;
            const int di = idx & 31;
            const float pa = Pa[i0 + di];
            const float4* src = (const float4*)(B + ((size_t)(k0 + dk) * KD + (i0 + di)) * 8);
            float bv[8];
            ((float4*)bv)[0] = src[0];
            ((float4*)bv)[1] = src[1];
            #pragma unroll
            for (int y = 0; y < 8; ++y)
                lds[(y * 32 + di) * 24 + dk] = f2bf(bv[y] * pa);
        }
        __syncthreads();
        #pragma unroll
        for (int p = 0; p < 2; ++p) {
            const int c = t + p * 256;
            const int y = c >> 6;
            const int rem = c & 63;
            const int di = rem >> 1;
            const int dk8 = (rem & 1) * 8;
            uint4 v = *(const uint4*)&lds[(y * 32 + di) * 24 + dk8];
            *(uint4*)(Xbf + (size_t)y * PLANE + (size_t)(i0 + di) * KD + k0 + dk8) = v;
        }
    }
}

// ---------------------------------------------------------------------------
// GEMM + fused C-contraction + tail finalize (512 blocks, all co-resident).
// bid>>3 = (x,y) pair; bid&7 -> XCD-stable pair of 128x128 (i,j) tiles.
// K-loop: BK=64, global_load_lds width-16 staging, 16x16x32 bf16 MFMA.
// Epilogue: probs[x,y,z] += sum T[i,j]*C[i,j,z], wave shuffle-reduce,
// atomicAdd. Last block (fence+counter) computes KL and writes out.
// ---------------------------------------------------------------------------
__global__ __launch_bounds__(256, 2) void gemm_kernel(
        const float* __restrict__ yp, const float* __restrict__ yt,
        const unsigned short* __restrict__ Wbf,
        const unsigned short* __restrict__ Xbf,
        float* __restrict__ probs_acc, unsigned int* __restrict__ counter,
        float* __restrict__ out) {

    __shared__ unsigned short stage[2][128 * 64];   // [0]=Xs [1]=Ws, 32 KB
    __shared__ float red[4][8];
    __shared__ int is_last;

    const int b = blockIdx.x;
    const int t = threadIdx.x;
    const int w = t >> 6;          // wave 0..3
    const int l = t & 63;

    const int pair = b >> 3;               // 0..63
    const int xx = pair >> 3, yy = pair & 7;
    const int sub = b & 7;
    const unsigned short* Xg = Xbf + (size_t)yy * PLANE;
    const unsigned short* Wg = Wbf + (size_t)xx * PLANE;
    const float* Cptr = yp + 3 * KD + 2 * (size_t)SZ;

    const int wm = w >> 1, wn = w & 1;
    const int lm = l & 15, quad = l >> 4;
    const int row8 = l >> 3, ch = l & 7;   // staging lane geometry

    for (int tt = 0; tt < 2; ++tt) {
        const int tile = sub * 2 + tt;             // 0..15
        const int i0 = (tile >> 2) * 128;
        const int j0 = (tile & 3) * 128;

        v4f acc[4][4];
        #pragma unroll
        for (int mt = 0; mt < 4; ++mt)
            #pragma unroll
            for (int nt = 0; nt < 4; ++nt)
                acc[mt][nt] = (v4f){0.f, 0.f, 0.f, 0.f};

        for (int kt = 0; kt < 8; ++kt) {
            const int kb = kt * 64;
            #pragma unroll
            for (int a = 0; a < 4; ++a) {
                const int r = w * 32 + a * 8;
                async16(Xg + (size_t)(i0 + r + row8) * KD + kb + ch * 8,
                        &stage[0][r * 64]);
                async16(Wg + (size_t)(j0 + r + row8) * KD + kb + ch * 8,
                        &stage[1][r * 64]);
            }
            __syncthreads();

            #pragma unroll
            for (int s = 0; s < 2; ++s) {
                v8s aF[4], bF[4];
                #pragma unroll
                for (int mt = 0; mt < 4; ++mt)
                    aF[mt] = *(const v8s*)&stage[0][(wm * 64 + mt * 16 + lm) * 64 + s * 32 + quad * 8];
                #pragma unroll
                for (int nt = 0; nt < 4; ++nt)
                    bF[nt] = *(const v8s*)&stage[1][(wn * 64 + nt * 16 + lm) * 64 + s * 32 + quad * 8];
                #pragma unroll
                for (int mt = 0; mt < 4; ++mt)
                    #pragma unroll
                    for (int nt = 0; nt < 4; ++nt)
                        acc[mt][nt] = __builtin_amdgcn_mfma_f32_16x16x32_bf16(
                            aF[mt], bF[nt], acc[mt][nt], 0, 0, 0);
            }
            __syncthreads();
        }

        // epilogue: probs[x,y,z] += sum_{i,j} T[i,j]*C[i,j,z]
        float zacc[8];
        #pragma unroll
        for (int z = 0; z < 8; ++z) zacc[z] = 0.f;
        #pragma unroll
        for (int mt = 0; mt < 4; ++mt) {
            #pragma unroll
            for (int nt = 0; nt < 4; ++nt) {
                #pragma unroll
                for (int r = 0; r < 4; ++r) {
                    const int gi = i0 + wm * 64 + mt * 16 + quad * 4 + r;  // D row = i
                    const int gj = j0 + wn * 64 + nt * 16 + lm;            // D col = j
                    const float4* cp = (const float4*)(Cptr + ((size_t)gi * KD + gj) * 8);
                    const float4 c0 = cp[0], c1 = cp[1];
                    const float tv = acc[mt][nt][r];
                    zacc[0] += tv * c0.x; zacc[1] += tv * c0.y;
                    zacc[2] += tv * c0.z; zacc[3] += tv * c0.w;
                    zacc[4] += tv * c1.x; zacc[5] += tv * c1.y;
                    zacc[6] += tv * c1.z; zacc[7] += tv * c1.w;
                }
            }
        }
        #pragma unroll
        for (int z = 0; z < 8; ++z) {
            float v = zacc[z];
            for (int off = 32; off > 0; off >>= 1)
                v += __shfl_xor(v, off, 64);
            zacc[z] = v;
        }
        if (l == 0) {
            #pragma unroll
            for (int z = 0; z < 8; ++z) red[w][z] = zacc[z];
        }
        __syncthreads();
        if (t < 8) {
            const float s = red[0][t] + red[1][t] + red[2][t] + red[3][t];
            atomicAdd(&probs_acc[(xx * 8 + yy) * 8 + t], s);
        }
        __syncthreads();   // protect red[] before next tile reuses it
    }

    // ---- last-block finalize (fence + counter, no extra launch) ----
    __threadfence();
    __syncthreads();
    if (t == 0) {
        const unsigned int old = atomicAdd(counter, 1u);
        is_last = (old == (unsigned int)(gridDim.x - 1));
    }
    __syncthreads();
    if (is_last) {
        __threadfence();
        float term = 0.f;
        #pragma unroll
        for (int h = 0; h < 2; ++h) {
            const int idx = t + h * 256;
            // coherent read: same path as the writes
            const float p = atomicAdd(&probs_acc[idx], 0.0f);
            out[1 + idx] = p;
            const float ytv = yt[idx];
            const float pc = fminf(fmaxf(p, 1e-10f), 1.0f);
            term += ytv * (logf(ytv + 1e-10f) - logf(pc));
        }
        for (int off = 32; off > 0; off >>= 1)
            term += __shfl_xor(term, off, 64);
        if (l == 0) red[w][0] = term;
        __syncthreads();
        if (t == 0)
            out[0] = red[0][0] + red[1][0] + red[2][0] + red[3][0];
    }
}

extern "C" void kernel_launch(void* const* d_in, const int* in_sizes, int n_in,
                              void* d_out, int out_size, void* d_ws, size_t ws_size,
                              hipStream_t stream) {
    const float* yp = (const float*)d_in[0];
    const float* yt = (const float*)d_in[1];
    float* out = (float*)d_out;

    unsigned short* Wbf = (unsigned short*)d_ws;              // 4 MB
    unsigned short* Xbf = Wbf + (size_t)8 * PLANE;            // 4 MB
    float* probs_acc = (float*)(Xbf + (size_t)8 * PLANE);     // 512 floats
    unsigned int* counter = (unsigned int*)(probs_acc + 512);

    pack_kernel<<<512, 256, 0, stream>>>(yp, Wbf, Xbf, probs_acc, counter);
    gemm_kernel<<<512, 256, 0, stream>>>(yp, yt, Wbf, Xbf, probs_acc, counter, out);
}